// Round 4
// baseline (219.772 us; speedup 1.0000x reference)
//
#include <hip/hip_runtime.h>
#include <hip/hip_bf16.h>

#define BB 4
#define HH 128
#define WW 128
#define CC 32
#define OH 120
#define OW 120
#define KT 25
#define OFFC 100
#define FF 64

typedef __attribute__((ext_vector_type(8))) short bf16x8;
typedef __attribute__((ext_vector_type(4))) float f32x4;

// d_ws layout (bf16/short elements):
//   WB:  [25 taps][7 n][64 lane][8]   89,600   (offset-conv weights, B-frag)
//   WD:  [4 n][25 taps][64 lane][8]   51,200   (dcn weights, B-frag)
//   V16: bf16 volume [B][H][W][C]  2,097,152
#define WB_ELEMS   (KT * 7 * 64 * 8)
#define WD_ELEMS   (4 * KT * 64 * 8)
#define VOL_UNITS  (BB * HH * WW * CC / 8)
#define VOL16_OFF  (WB_ELEMS + WD_ELEMS)

__device__ __forceinline__ short f2bf(float x) {
    __hip_bfloat16 h = __float2bfloat16(x);
    return *reinterpret_cast<short*>(&h);
}

// ---------------------------------------------------------------------------
// Repack: weights -> MFMA B-fragment layout; volume fp32 -> bf16.
// ---------------------------------------------------------------------------
__global__ __launch_bounds__(256) void repack_kernel(
    const float* __restrict__ volume, const float* __restrict__ w_off,
    const float* __restrict__ w_dcn, short* __restrict__ ws)
{
    int idx = blockIdx.x * 256 + threadIdx.x;
    short* WB  = ws;
    short* WD  = ws + WB_ELEMS;
    short* V16 = ws + VOL16_OFF;
    if (idx < WB_ELEMS) {
        int j = idx & 7, l = (idx >> 3) & 63;
        int tn = idx >> 9;            // t*7 + n
        int n = tn % 7, t = tn / 7;
        int c = (l >> 4) * 8 + j;
        int oc = n * 16 + (l & 15);
        float v = (oc < OFFC) ? w_off[(t * CC + c) * OFFC + oc] : 0.f;
        WB[idx] = f2bf(v);
    } else if (idx < WB_ELEMS + WD_ELEMS) {
        int idx2 = idx - WB_ELEMS;
        int j = idx2 & 7, l = (idx2 >> 3) & 63;
        int nt = idx2 >> 9;           // n*25 + t
        int t = nt % KT, n = nt / KT;
        int c = (l >> 4) * 8 + j;
        int f = n * 16 + (l & 15);
        WD[idx2] = f2bf(w_dcn[(t * CC + c) * FF + f]);
    } else {
        int v = idx - (WB_ELEMS + WD_ELEMS);
        if (v < VOL_UNITS) {
            const float* src = volume + (size_t)v * 8;
            float4 q0 = *(const float4*)src;
            float4 q1 = *(const float4*)(src + 4);
            alignas(16) short tmp[8];
            tmp[0] = f2bf(q0.x); tmp[1] = f2bf(q0.y); tmp[2] = f2bf(q0.z); tmp[3] = f2bf(q0.w);
            tmp[4] = f2bf(q1.x); tmp[5] = f2bf(q1.y); tmp[6] = f2bf(q1.z); tmp[7] = f2bf(q1.w);
            *(bf16x8*)&V16[(size_t)v * 8] = *(const bf16x8*)tmp;
        }
    }
}

// ---------------------------------------------------------------------------
// Fused kernel: per block = 16 consecutive pixels of one output row.
//  P1: stage 9x24x32 bf16 patch (swizzled LDS)
//  P2: offset GEMM (M=16,N=112,K=800) -> offtile in LDS (f32)
//  P3: per-(p,t,g) position precompute -> posr in LDS (clipped py,px)
//  P4: einsum with inline gather: lane builds its own A-frag (4 corner loads
//      + bilinear combine for its 8 channels), MFMA with WD B-frags.
// ---------------------------------------------------------------------------
__global__ __launch_bounds__(256) void dcn_fused(
    const short* __restrict__ ws_ro, const float* __restrict__ b_off,
    const float* __restrict__ b_dcn, float* __restrict__ out)
{
    __shared__ short patchU[864 * 8];      // 13,824 B: [9 rows][24 cols][4 cq]
    __shared__ float offtile[16 * 101];    //  6,464 B
    __shared__ float posr[1600];           //  6,400 B: [800 items][py,px]

    const short* WB  = ws_ro;
    const short* WD  = ws_ro + WB_ELEMS;
    const short* V16 = ws_ro + VOL16_OFF;

    const int tid  = threadIdx.x;
    const int lane = tid & 63;
    const int wv   = tid >> 6;
    const int bxb = blockIdx.x, oy = blockIdx.y, b = blockIdx.z;
    const int ox0 = bxb * 16;
    const short* Vb = V16 + (size_t)b * HH * WW * CC;

    // ---- P1: stage patch rows [oy, oy+9), cols [ox0, ox0+24) (col-clamped)
    for (int i = tid; i < 864; i += 256) {
        int cq = i & 3;
        int xx = (i >> 2) % 24;
        int yy = (i >> 2) / 24;
        int col = ox0 + xx; col = (col < WW) ? col : (WW - 1);
        bf16x8 val = *(const bf16x8*)&Vb[((size_t)(oy + yy) * WW + col) * CC + cq * 8];
        int u = ((yy * 24 + xx) << 2) + (cq ^ (xx & 3) ^ ((xx >> 2) & 3));
        *(bf16x8*)&patchU[u * 8] = val;
    }
    __syncthreads();

    // ---- P2: offset GEMM. wave wv: n-tiles {2wv, 2wv+1<7}
    {
        const int p  = lane & 15;
        const int cq = lane >> 4;
        const int n0 = wv * 2, n1 = wv * 2 + 1;
        f32x4 a0 = (f32x4){0.f, 0.f, 0.f, 0.f};
        f32x4 a1 = (f32x4){0.f, 0.f, 0.f, 0.f};
        for (int fh = 0; fh < 5; ++fh) {
            #pragma unroll
            for (int fw = 0; fw < 5; ++fw) {
                int t = fh * 5 + fw;
                int x = p + 2 * fw;
                int u = (((2 * fh) * 24 + x) << 2) + (cq ^ (x & 3) ^ ((x >> 2) & 3));
                bf16x8 af = *(const bf16x8*)&patchU[u * 8];
                bf16x8 b0 = *(const bf16x8*)&WB[((t * 7 + n0) << 9) + lane * 8];
                a0 = __builtin_amdgcn_mfma_f32_16x16x32_bf16(af, b0, a0, 0, 0, 0);
                if (n1 < 7) {
                    bf16x8 b1 = *(const bf16x8*)&WB[((t * 7 + n1) << 9) + lane * 8];
                    a1 = __builtin_amdgcn_mfma_f32_16x16x32_bf16(af, b1, a1, 0, 0, 0);
                }
            }
        }
        // epilogue: C layout col=lane&15, row=(lane>>4)*4+r
        const int col = lane & 15, q = lane >> 4;
        {
            int oc = n0 * 16 + col;
            if (oc < OFFC) {
                float bo = b_off[oc];
                #pragma unroll
                for (int r = 0; r < 4; ++r)
                    offtile[(q * 4 + r) * 101 + oc] = a0[r] + bo;
            }
        }
        if (n1 < 7) {
            int oc = n1 * 16 + col;
            if (oc < OFFC) {
                float bo = b_off[oc];
                #pragma unroll
                for (int r = 0; r < 4; ++r)
                    offtile[(q * 4 + r) * 101 + oc] = a1[r] + bo;
            }
        }
    }
    __syncthreads();

    // ---- P3: position precompute for 800 (p,t,g) items
    for (int item = tid; item < 800; item += 256) {
        int p = item / 50;
        int r = item - p * 50;
        int t = r >> 1, g = r & 1;
        int t5 = t / 5, tm5 = t - t5 * 5;
        float dy = offtile[p * 101 + t * 4 + g];
        float dx = offtile[p * 101 + t * 4 + 2 + g];
        float py = (float)(oy + 2 * t5) + dy;
        float px = (float)(ox0 + p + 2 * tm5) + dx;
        py = fminf(fmaxf(py, 0.f), 127.f);
        px = fminf(fmaxf(px, 0.f), 127.f);
        posr[item * 2]     = py;
        posr[item * 2 + 1] = px;
    }
    __syncthreads();

    // ---- P4: einsum with inline gather. wave wv -> f-tile wv, g = wv>>1.
    {
        const int p  = lane & 15;
        const int cq = lane >> 4;
        const int g  = wv >> 1;
        const short* wd = WD + (wv * KT) * 512 + lane * 8;
        f32x4 accA = (f32x4){0.f, 0.f, 0.f, 0.f};
        f32x4 accB = (f32x4){0.f, 0.f, 0.f, 0.f};
        for (int t = 0; t < KT; ++t) {
            float2 pp = *(const float2*)&posr[(p * 50 + t * 2 + g) * 2];
            float py = pp.x, px = pp.y;
            float y0f = fminf(floorf(py), 126.f);
            float x0f = fminf(floorf(px), 126.f);
            float wy = py - y0f, wx = px - x0f;
            int y0 = (int)y0f, x0 = (int)x0f;
            float w00 = (1.f - wy) * (1.f - wx);
            float w01 = (1.f - wy) * wx;
            float w10 = wy * (1.f - wx);
            float w11 = wy * wx;
            const short* vb = Vb + ((size_t)(y0 * WW + x0)) * CC + cq * 8;
            uint4 Au = *(const uint4*)vb;
            uint4 Bu = *(const uint4*)(vb + CC);
            uint4 Cu = *(const uint4*)(vb + WW * CC);
            uint4 Du = *(const uint4*)(vb + WW * CC + CC);
            alignas(16) short tmp[8];
            #pragma unroll
            for (int i = 0; i < 4; ++i) {
                unsigned au = ((const unsigned*)&Au)[i];
                unsigned bu = ((const unsigned*)&Bu)[i];
                unsigned cu = ((const unsigned*)&Cu)[i];
                unsigned du = ((const unsigned*)&Du)[i];
                float alo = __uint_as_float(au << 16), ahi = __uint_as_float(au & 0xffff0000u);
                float blo = __uint_as_float(bu << 16), bhi = __uint_as_float(bu & 0xffff0000u);
                float clo = __uint_as_float(cu << 16), chi = __uint_as_float(cu & 0xffff0000u);
                float dlo = __uint_as_float(du << 16), dhi = __uint_as_float(du & 0xffff0000u);
                float rlo = alo * w00 + blo * w01 + clo * w10 + dlo * w11;
                float rhi = ahi * w00 + bhi * w01 + chi * w10 + dhi * w11;
                tmp[2 * i]     = f2bf(rlo);
                tmp[2 * i + 1] = f2bf(rhi);
            }
            bf16x8 af = *(const bf16x8*)tmp;
            bf16x8 bf = *(const bf16x8*)&wd[t * 512];
            if (t & 1) accB = __builtin_amdgcn_mfma_f32_16x16x32_bf16(af, bf, accB, 0, 0, 0);
            else       accA = __builtin_amdgcn_mfma_f32_16x16x32_bf16(af, bf, accA, 0, 0, 0);
        }
        const int f = wv * 16 + (lane & 15);
        const float bd = b_dcn[f];
        const long pix0 = ((long)b * OH + oy) * OW + ox0;
        #pragma unroll
        for (int r = 0; r < 4; ++r) {
            int pp = (lane >> 4) * 4 + r;
            if (ox0 + pp < OW)
                out[(pix0 + pp) * FF + f] = accA[r] + accB[r] + bd;
        }
    }
}

extern "C" void kernel_launch(void* const* d_in, const int* in_sizes, int n_in,
                              void* d_out, int out_size, void* d_ws, size_t ws_size,
                              hipStream_t stream) {
    const float* volume = (const float*)d_in[0];
    const float* w_off  = (const float*)d_in[1];
    const float* b_off  = (const float*)d_in[2];
    const float* w_dcn  = (const float*)d_in[3];
    const float* b_dcn  = (const float*)d_in[4];
    float* out = (float*)d_out;
    short* ws  = (short*)d_ws;   // 4.48 MB used

    int repack_blocks = (WB_ELEMS + WD_ELEMS + VOL_UNITS + 255) / 256;
    repack_kernel<<<repack_blocks, 256, 0, stream>>>(volume, w_off, w_dcn, ws);

    dim3 g2(8, OH, BB);   // 8 x 120 x 4 = 3840 blocks
    dcn_fused<<<g2, 256, 0, stream>>>(ws, b_off, b_dcn, out);
}

// Round 5
// 152.698 us; speedup vs baseline: 1.4393x; 1.4393x over previous
//
#include <hip/hip_runtime.h>
#include <hip/hip_bf16.h>

#define BB 4
#define HH 128
#define WW 128
#define CC 32
#define OH 120
#define OW 120
#define KT 25
#define OFFC 100
#define FF 64
#define NPX 32
#define NTHREADS 512

typedef __attribute__((ext_vector_type(8))) short bf16x8;
typedef __attribute__((ext_vector_type(4))) float f32x4;

// d_ws layout (short elements):
//   WB:  [25 taps][7 n][64 lane][8]   89,600   (offset-conv weights, B-frag)
//   WD:  [4 n][25 taps][64 lane][8]   51,200   (dcn weights, B-frag)
//   V16: bf16 volume [B][H][W][C]  2,097,152
#define WB_ELEMS   (KT * 7 * 64 * 8)
#define WD_ELEMS   (4 * KT * 64 * 8)
#define VOL_UNITS  (BB * HH * WW * CC / 8)
#define VOL16_OFF  (WB_ELEMS + WD_ELEMS)

__device__ __forceinline__ short f2bf(float x) {
    __hip_bfloat16 h = __float2bfloat16(x);
    return *reinterpret_cast<short*>(&h);
}
__device__ __forceinline__ float asf(unsigned u) { return __uint_as_float(u); }

// ---------------------------------------------------------------------------
// Repack: weights -> MFMA B-fragment layout; volume fp32 -> bf16.
// ---------------------------------------------------------------------------
__global__ __launch_bounds__(256) void repack_kernel(
    const float* __restrict__ volume, const float* __restrict__ w_off,
    const float* __restrict__ w_dcn, short* __restrict__ ws)
{
    int idx = blockIdx.x * 256 + threadIdx.x;
    short* WB  = ws;
    short* WD  = ws + WB_ELEMS;
    short* V16 = ws + VOL16_OFF;
    if (idx < WB_ELEMS) {
        int j = idx & 7, l = (idx >> 3) & 63;
        int tn = idx >> 9;            // t*7 + n
        int n = tn % 7, t = tn / 7;
        int c = (l >> 4) * 8 + j;
        int oc = n * 16 + (l & 15);
        float v = (oc < OFFC) ? w_off[(t * CC + c) * OFFC + oc] : 0.f;
        WB[idx] = f2bf(v);
    } else if (idx < WB_ELEMS + WD_ELEMS) {
        int idx2 = idx - WB_ELEMS;
        int j = idx2 & 7, l = (idx2 >> 3) & 63;
        int nt = idx2 >> 9;           // n*25 + t
        int t = nt % KT, n = nt / KT;
        int c = (l >> 4) * 8 + j;
        int f = n * 16 + (l & 15);
        WD[idx2] = f2bf(w_dcn[(t * CC + c) * FF + f]);
    } else {
        int v = idx - (WB_ELEMS + WD_ELEMS);
        if (v < VOL_UNITS) {
            const float* src = volume + (size_t)v * 8;
            float4 q0 = *(const float4*)src;
            float4 q1 = *(const float4*)(src + 4);
            alignas(16) short tmp[8];
            tmp[0] = f2bf(q0.x); tmp[1] = f2bf(q0.y); tmp[2] = f2bf(q0.z); tmp[3] = f2bf(q0.w);
            tmp[4] = f2bf(q1.x); tmp[5] = f2bf(q1.y); tmp[6] = f2bf(q1.z); tmp[7] = f2bf(q1.w);
            *(bf16x8*)&V16[(size_t)v * 8] = *(const bf16x8*)tmp;
        }
    }
}

// ---------------------------------------------------------------------------
// Fused kernel: block = 32 px of one output row, 512 threads (8 waves).
//  P1: stage 9x40x32 bf16 patch (swizzled)          -> region0
//  P2: offset GEMM, waves 0-6 = n-tiles, 2 M-tiles  -> offtile (region1)
//  P3: 1600 items: pos+weights packed uint4         -> pos4 (region0, over patch)
//  P4: dedup gather+einsum: wave=(mt,g,t-half), af built once, 2 MFMAs/af,
//      2-deep software pipeline; partial-acc reduce via red (region1).
// ---------------------------------------------------------------------------
__global__ __launch_bounds__(512, 4) void dcn_fused(
    const short* __restrict__ ws_ro, const float* __restrict__ b_off,
    const float* __restrict__ b_dcn, float* __restrict__ out)
{
    __shared__ __align__(16) char smem[38528];
    short* patch   = (short*)smem;             // 23,040 B
    uint4* pos4    = (uint4*)smem;             // 25,600 B (after patch dead)
    float* offtile = (float*)(smem + 25600);   // 12,928 B
    f32x4* red     = (f32x4*)(smem + 25600);   //  8,192 B (after offtile dead)

    const short* WB  = ws_ro;
    const short* WD  = ws_ro + WB_ELEMS;
    const short* V16 = ws_ro + VOL16_OFF;

    const int tid  = threadIdx.x;
    const int lane = tid & 63;
    const int wv   = tid >> 6;
    const int ox0  = blockIdx.x * NPX;
    const int oy   = blockIdx.y;
    const int b    = blockIdx.z;
    const short* Vb = V16 + (size_t)b * (HH * WW * CC);

    // ---- P1: stage patch rows [oy,oy+9), cols [ox0,ox0+40) (col-clamped)
    for (int i = tid; i < 9 * 40 * 4; i += NTHREADS) {
        int cq = i & 3;
        int xi = (i >> 2) % 40;
        int yi = (i >> 2) / 40;
        int col = ox0 + xi; col = (col < WW) ? col : (WW - 1);
        bf16x8 v = *(const bf16x8*)&Vb[((size_t)(oy + yi) * WW + col) * CC + cq * 8];
        int u = ((yi * 40 + xi) << 2) + (cq ^ (xi & 3) ^ ((xi >> 2) & 3));
        *(bf16x8*)&patch[u * 8] = v;
    }
    __syncthreads();

    // ---- P2: offset GEMM. wave w<7 -> n-tile w, both M-tiles.
    if (wv < 7) {
        const int pr = lane & 15, cq = lane >> 4;
        f32x4 a0 = (f32x4){0.f, 0.f, 0.f, 0.f};
        f32x4 a1 = (f32x4){0.f, 0.f, 0.f, 0.f};
        for (int fh = 0; fh < 5; ++fh) {
            #pragma unroll
            for (int fw = 0; fw < 5; ++fw) {
                int t = fh * 5 + fw;
                int x0 = pr + 2 * fw, x1 = x0 + 16;
                bf16x8 af0 = *(const bf16x8*)&patch[((((2 * fh) * 40 + x0) << 2) + (cq ^ (x0 & 3) ^ ((x0 >> 2) & 3))) * 8];
                bf16x8 af1 = *(const bf16x8*)&patch[((((2 * fh) * 40 + x1) << 2) + (cq ^ (x1 & 3) ^ ((x1 >> 2) & 3))) * 8];
                bf16x8 bf = *(const bf16x8*)&WB[(t * 7 + wv) * 512 + lane * 8];
                a0 = __builtin_amdgcn_mfma_f32_16x16x32_bf16(af0, bf, a0, 0, 0, 0);
                a1 = __builtin_amdgcn_mfma_f32_16x16x32_bf16(af1, bf, a1, 0, 0, 0);
            }
        }
        int col = lane & 15, q = lane >> 4;
        int oc = wv * 16 + col;
        if (oc < OFFC) {
            float bo = b_off[oc];
            #pragma unroll
            for (int r = 0; r < 4; ++r) {
                offtile[(q * 4 + r) * 101 + oc]        = a0[r] + bo;
                offtile[(16 + q * 4 + r) * 101 + oc]   = a1[r] + bo;
            }
        }
    }
    __syncthreads();

    // ---- P3: positions + bilinear weights, packed. Overwrites patch region.
    for (int item = tid; item < 1600; item += NTHREADS) {
        int p = item & 31, g = (item >> 5) & 1, t = item >> 6;
        int t5 = t / 5, tm5 = t - t5 * 5;
        float dy = offtile[p * 101 + t * 4 + g];
        float dx = offtile[p * 101 + t * 4 + 2 + g];
        float py = (float)(oy + 2 * t5) + dy;
        float px = (float)(ox0 + p + 2 * tm5) + dx;
        py = fminf(fmaxf(py, 0.f), 127.f);
        px = fminf(fmaxf(px, 0.f), 127.f);
        float y0f = fminf(floorf(py), 126.f);
        float x0f = fminf(floorf(px), 126.f);
        float wy = py - y0f, wx = px - x0f;
        int y0 = (int)y0f, x0i = (int)x0f;
        float w00 = (1.f - wy) * (1.f - wx);
        float w01 = (1.f - wy) * wx;
        float w10 = wy * (1.f - wx);
        float w11 = wy * wx;
        unsigned off = (unsigned)((y0 << 12) + (x0i << 5));   // element offset
        unsigned wlo = ((unsigned)(unsigned short)f2bf(w00)) | (((unsigned)(unsigned short)f2bf(w01)) << 16);
        unsigned whi = ((unsigned)(unsigned short)f2bf(w10)) | (((unsigned)(unsigned short)f2bf(w11)) << 16);
        pos4[((t * 2 + g) << 5) + p] = make_uint4(off, wlo, whi, 0u);
    }
    __syncthreads();

    // ---- P4: gather + einsum. wave = (mt, g, t-half). af built once, 2 MFMAs.
    const int mt = wv >> 2, gg = (wv >> 1) & 1, th = wv & 1;
    const int t0 = th ? 13 : 0, t1 = th ? 25 : 13;
    const int p  = mt * 16 + (lane & 15);
    const int cq = lane >> 4;
    const short* vcq = Vb + cq * 8;
    const short* wd0 = WD + ((gg * 2 + 0) * KT) * 512 + lane * 8;
    const short* wd1 = WD + ((gg * 2 + 1) * KT) * 512 + lane * 8;
    f32x4 acc0 = (f32x4){0.f, 0.f, 0.f, 0.f};
    f32x4 acc1 = (f32x4){0.f, 0.f, 0.f, 0.f};

    uint4 pwA = pos4[((t0 * 2 + gg) << 5) + p];
    uint4 pwB = pos4[(((t0 + 1) * 2 + gg) << 5) + p];
    {
        const short* vb0 = vcq + pwA.x;
        uint4 cA = *(const uint4*)(vb0);
        uint4 cB = *(const uint4*)(vb0 + 32);
        uint4 cC = *(const uint4*)(vb0 + 4096);
        uint4 cD = *(const uint4*)(vb0 + 4128);
        for (int t = t0; t < t1; ++t) {
            int tp = (t + 2 < t1) ? (t + 2) : (t1 - 1);
            uint4 pwC = pos4[((tp * 2 + gg) << 5) + p];
            const short* vbN = vcq + pwB.x;
            uint4 nA = *(const uint4*)(vbN);
            uint4 nB = *(const uint4*)(vbN + 32);
            uint4 nC = *(const uint4*)(vbN + 4096);
            uint4 nD = *(const uint4*)(vbN + 4128);

            float w00 = asf(pwA.y << 16), w01 = asf(pwA.y & 0xffff0000u);
            float w10 = asf(pwA.z << 16), w11 = asf(pwA.z & 0xffff0000u);
            alignas(16) short tmp[8];
            #define COMB(au, bu, cu, du, k)                                          \
                {                                                                    \
                    float lo = asf((au) << 16) * w00 + asf((bu) << 16) * w01         \
                             + asf((cu) << 16) * w10 + asf((du) << 16) * w11;        \
                    float hi = asf((au) & 0xffff0000u) * w00 + asf((bu) & 0xffff0000u) * w01 \
                             + asf((cu) & 0xffff0000u) * w10 + asf((du) & 0xffff0000u) * w11; \
                    tmp[2 * (k)] = f2bf(lo); tmp[2 * (k) + 1] = f2bf(hi);            \
                }
            COMB(cA.x, cB.x, cC.x, cD.x, 0)
            COMB(cA.y, cB.y, cC.y, cD.y, 1)
            COMB(cA.z, cB.z, cC.z, cD.z, 2)
            COMB(cA.w, cB.w, cC.w, cD.w, 3)
            #undef COMB
            bf16x8 af = *(const bf16x8*)tmp;
            acc0 = __builtin_amdgcn_mfma_f32_16x16x32_bf16(af, *(const bf16x8*)&wd0[t * 512], acc0, 0, 0, 0);
            acc1 = __builtin_amdgcn_mfma_f32_16x16x32_bf16(af, *(const bf16x8*)&wd1[t * 512], acc1, 0, 0, 0);
            pwA = pwB; pwB = pwC;
            cA = nA; cB = nB; cC = nC; cD = nD;
        }
    }
    __syncthreads();   // P4 reads of pos4/offtile done everywhere

    if (th) {
        int slot = wv >> 1;   // 0..3
        red[(slot * 2 + 0) * 64 + lane] = acc0;
        red[(slot * 2 + 1) * 64 + lane] = acc1;
    }
    __syncthreads();
    if (!th) {
        int slot = wv >> 1;
        acc0 += red[(slot * 2 + 0) * 64 + lane];
        acc1 += red[(slot * 2 + 1) * 64 + lane];
        int col = lane & 15, q = lane >> 4;
        int f0 = (gg * 2 + 0) * 16 + col;
        int f1 = (gg * 2 + 1) * 16 + col;
        float bd0 = b_dcn[f0], bd1 = b_dcn[f1];
        long pix0 = ((long)b * OH + oy) * OW + ox0;
        #pragma unroll
        for (int r = 0; r < 4; ++r) {
            int pp = mt * 16 + q * 4 + r;
            if (ox0 + pp < OW) {
                out[(pix0 + pp) * FF + f0] = acc0[r] + bd0;
                out[(pix0 + pp) * FF + f1] = acc1[r] + bd1;
            }
        }
    }
}

extern "C" void kernel_launch(void* const* d_in, const int* in_sizes, int n_in,
                              void* d_out, int out_size, void* d_ws, size_t ws_size,
                              hipStream_t stream) {
    const float* volume = (const float*)d_in[0];
    const float* w_off  = (const float*)d_in[1];
    const float* b_off  = (const float*)d_in[2];
    const float* w_dcn  = (const float*)d_in[3];
    const float* b_dcn  = (const float*)d_in[4];
    float* out = (float*)d_out;
    short* ws  = (short*)d_ws;   // 4.48 MB used

    int repack_blocks = (WB_ELEMS + WD_ELEMS + VOL_UNITS + 255) / 256;
    repack_kernel<<<repack_blocks, 256, 0, stream>>>(volume, w_off, w_dcn, ws);

    dim3 g2((OW + NPX - 1) / NPX, OH, BB);   // 4 x 120 x 4 = 1920 blocks
    dcn_fused<<<g2, NTHREADS, 0, stream>>>(ws, b_off, b_dcn, out);
}